// Round 1
// baseline (161.551 us; speedup 1.0000x reference)
//
#include <hip/hip_runtime.h>

// One row (128 f32) per 32-lane half-wave. Each lane loads float4 (16B),
// computes partials of the two dot products, butterfly-reduces within the
// half, lane (tid&31)==0 runs the scalar 5-stage chain and writes out[row].

__global__ __launch_bounds__(256) void funcblock_kernel(
    const float* __restrict__ x,
    const float* __restrict__ W_prod, const float* __restrict__ b_prod,
    const float* __restrict__ W_sum,  const float* __restrict__ b_sum,
    const float* __restrict__ w_dln,  const float* __restrict__ W_ln,
    const float* __restrict__ w_dsin, const float* __restrict__ W_sin,
    const float* __restrict__ w_dcos, const float* __restrict__ W_cos,
    const float* __restrict__ w_de,   const float* __restrict__ W_e,
    const float* __restrict__ w_dtanh,const float* __restrict__ W_tanh,
    float* __restrict__ out, int B)
{
    const int lane = threadIdx.x & 31;                       // lane within half-wave
    const int halves_per_block = blockDim.x >> 5;            // 8
    const int half_in_block = threadIdx.x >> 5;
    const int halves_total = gridDim.x * halves_per_block;
    const int half_id0 = blockIdx.x * halves_per_block + half_in_block;

    // Loop-invariant weights -> registers (uniform, compiler scalarizes)
    const float4 wp = reinterpret_cast<const float4*>(W_prod)[lane];
    const float4 ws = reinterpret_cast<const float4*>(W_sum)[lane];
    const float ws128 = W_sum[128];
    const float bp = b_prod[0], bs = b_sum[0];
    const float wdln  = w_dln[0],  wln0  = W_ln[0],  wln1  = W_ln[1];
    const float wdsin = w_dsin[0], wsin0 = W_sin[0], wsin1 = W_sin[1];
    const float wdcos = w_dcos[0], wcos0 = W_cos[0], wcos1 = W_cos[1];
    const float wde   = w_de[0],   we0   = W_e[0],   we1   = W_e[1];
    const float wdtanh= w_dtanh[0],wt0   = W_tanh[0],wt1   = W_tanh[1];

    for (int row = half_id0; row < B; row += halves_total) {
        const float4 xv = reinterpret_cast<const float4*>(x + (size_t)row * 128)[lane];

        // ProductBlock partial: sum log|x| * W_prod
        float p = logf(fabsf(xv.x)) * wp.x;
        p += logf(fabsf(xv.y)) * wp.y;
        p += logf(fabsf(xv.z)) * wp.z;
        p += logf(fabsf(xv.w)) * wp.w;
        // SumBlock partial: sum x * W_sum[0:128]
        float s = xv.x * ws.x + xv.y * ws.y + xv.z * ws.z + xv.w * ws.w;

        // Butterfly reduce within the 32-lane half (xor masks <=16 stay in-half)
        #pragma unroll
        for (int m = 16; m >= 1; m >>= 1) {
            p += __shfl_xor(p, m, 64);
            s += __shfl_xor(s, m, 64);
        }

        if (lane == 0) {  // exec mask {0,32}: one masked pass covers both rows of the wave
            const float x_prod = expf(p + bp);
            float h = s + x_prod * ws128 + bs;
            float d;
            d = fmaxf(logf(fabsf(h)) * wdln, 0.0f);  h = d * wln0  + h * wln1;
            d = fmaxf(sinf(h) * wdsin, 0.0f);        h = d * wsin0 + h * wsin1;
            d = fmaxf(cosf(h) * wdcos, 0.0f);        h = d * wcos0 + h * wcos1;
            d = fmaxf(expf(h) * wde,   0.0f);        h = d * we0   + h * we1;
            d = fmaxf(tanhf(h) * wdtanh, 0.0f);      h = d * wt0   + h * wt1;
            out[row] = h;
        }
    }
}

extern "C" void kernel_launch(void* const* d_in, const int* in_sizes, int n_in,
                              void* d_out, int out_size, void* d_ws, size_t ws_size,
                              hipStream_t stream) {
    const float* x      = (const float*)d_in[0];
    const float* W_prod = (const float*)d_in[1];
    const float* b_prod = (const float*)d_in[2];
    const float* W_sum  = (const float*)d_in[3];
    const float* b_sum  = (const float*)d_in[4];
    const float* w_dln  = (const float*)d_in[5];
    const float* W_ln   = (const float*)d_in[6];
    const float* w_dsin = (const float*)d_in[7];
    const float* W_sin  = (const float*)d_in[8];
    const float* w_dcos = (const float*)d_in[9];
    const float* W_cos  = (const float*)d_in[10];
    const float* w_de   = (const float*)d_in[11];
    const float* W_e    = (const float*)d_in[12];
    const float* w_dtanh= (const float*)d_in[13];
    const float* W_tanh = (const float*)d_in[14];
    float* out = (float*)d_out;

    const int B = out_size;             // 1048576 rows
    const int block = 256;
    const int grid = 2048;              // 8 half-waves/block -> 16384 halves, grid-stride

    hipLaunchKernelGGL(funcblock_kernel, dim3(grid), dim3(block), 0, stream,
                       x, W_prod, b_prod, W_sum, b_sum,
                       w_dln, W_ln, w_dsin, W_sin, w_dcos, W_cos,
                       w_de, W_e, w_dtanh, W_tanh, out, B);
}

// Round 2
// 106.521 us; speedup vs baseline: 1.5166x; 1.5166x over previous
//
#include <hip/hip_runtime.h>

// Phase 1: half-wave (32 lanes) per row, float4/lane loads (512B/row, fully
// coalesced). Butterfly-reduce the two dots, park raw (p,s) per row in LDS.
// Phase 2: after 64 rows, all 64 lanes of the wave run the expensive
// exp + 5-stage transcendental chain wave-parallel (amortized 32x vs the
// old per-row masked execution) and store 64 coalesced outputs.

__global__ __launch_bounds__(256) void funcblock_kernel(
    const float* __restrict__ x,
    const float* __restrict__ W_prod, const float* __restrict__ b_prod,
    const float* __restrict__ W_sum,  const float* __restrict__ b_sum,
    const float* __restrict__ w_dln,  const float* __restrict__ W_ln,
    const float* __restrict__ w_dsin, const float* __restrict__ W_sin,
    const float* __restrict__ w_dcos, const float* __restrict__ W_cos,
    const float* __restrict__ w_de,   const float* __restrict__ W_e,
    const float* __restrict__ w_dtanh,const float* __restrict__ W_tanh,
    float* __restrict__ out, int B)
{
    __shared__ float pbuf[4][64];   // per-wave strip: raw product-dot per row
    __shared__ float sbuf[4][64];   // per-wave strip: raw sum-dot per row

    const int tid   = threadIdx.x;
    const int hlane = tid & 31;        // lane within half-wave
    const int half  = (tid >> 5) & 1;  // which half of the wave64
    const int wid   = tid >> 6;        // wave index in block (0..3)
    const int lane  = tid & 63;

    // Loop-invariant weights -> registers
    const float4 wp = reinterpret_cast<const float4*>(W_prod)[hlane];
    const float4 ws = reinterpret_cast<const float4*>(W_sum)[hlane];
    const float ws128 = W_sum[128];
    const float bp = b_prod[0], bs = b_sum[0];
    const float wdln  = w_dln[0],  wln0  = W_ln[0],  wln1  = W_ln[1];
    const float wdsin = w_dsin[0], wsin0 = W_sin[0], wsin1 = W_sin[1];
    const float wdcos = w_dcos[0], wcos0 = W_cos[0], wcos1 = W_cos[1];
    const float wde   = w_de[0],   we0   = W_e[0],   we1   = W_e[1];
    const float wdtanh= w_dtanh[0],wt0   = W_tanh[0],wt1   = W_tanh[1];

    const int rows_per_block = 256;    // 4 waves x 64 rows
    for (int base = blockIdx.x * rows_per_block; base < B;
         base += gridDim.x * rows_per_block) {
        const int wbase = base + wid * 64;

        // ---- Phase 1: dot products for 64 rows (2 rows per iteration) ----
        #pragma unroll 2
        for (int it = 0; it < 32; ++it) {
            const int row = wbase + half * 32 + it;
            float p = 0.0f, s = 0.0f;
            if (row < B) {
                const float4 xv =
                    reinterpret_cast<const float4*>(x + (size_t)row * 128)[hlane];
                p  = logf(fabsf(xv.x)) * wp.x;
                p += logf(fabsf(xv.y)) * wp.y;
                p += logf(fabsf(xv.z)) * wp.z;
                p += logf(fabsf(xv.w)) * wp.w;
                s  = xv.x * ws.x + xv.y * ws.y + xv.z * ws.z + xv.w * ws.w;
            }
            #pragma unroll
            for (int m = 16; m >= 1; m >>= 1) {   // stays within the 32-lane half
                p += __shfl_xor(p, m, 64);
                s += __shfl_xor(s, m, 64);
            }
            if (hlane == 0) {
                pbuf[wid][half * 32 + it] = p;
                sbuf[wid][half * 32 + it] = s;
            }
        }
        __syncthreads();

        // ---- Phase 2: chain for 64 rows, one per lane, all lanes active ----
        const int row = wbase + lane;
        const float p = pbuf[wid][lane];
        const float s = sbuf[wid][lane];
        __syncthreads();   // LDS strips free for next block-iteration

        float h = s + expf(p + bp) * ws128 + bs;
        float d;
        d = fmaxf(logf(fabsf(h)) * wdln, 0.0f);  h = d * wln0  + h * wln1;
        d = fmaxf(sinf(h) * wdsin, 0.0f);        h = d * wsin0 + h * wsin1;
        d = fmaxf(cosf(h) * wdcos, 0.0f);        h = d * wcos0 + h * wcos1;
        d = fmaxf(expf(h) * wde,   0.0f);        h = d * we0   + h * we1;
        d = fmaxf(tanhf(h) * wdtanh, 0.0f);      h = d * wt0   + h * wt1;
        if (row < B) out[row] = h;
    }
}

extern "C" void kernel_launch(void* const* d_in, const int* in_sizes, int n_in,
                              void* d_out, int out_size, void* d_ws, size_t ws_size,
                              hipStream_t stream) {
    const float* x      = (const float*)d_in[0];
    const float* W_prod = (const float*)d_in[1];
    const float* b_prod = (const float*)d_in[2];
    const float* W_sum  = (const float*)d_in[3];
    const float* b_sum  = (const float*)d_in[4];
    const float* w_dln  = (const float*)d_in[5];
    const float* W_ln   = (const float*)d_in[6];
    const float* w_dsin = (const float*)d_in[7];
    const float* W_sin  = (const float*)d_in[8];
    const float* w_dcos = (const float*)d_in[9];
    const float* W_cos  = (const float*)d_in[10];
    const float* w_de   = (const float*)d_in[11];
    const float* W_e    = (const float*)d_in[12];
    const float* w_dtanh= (const float*)d_in[13];
    const float* W_tanh = (const float*)d_in[14];
    float* out = (float*)d_out;

    const int B = out_size;     // 1048576 rows
    const int block = 256;      // 4 waves
    const int grid  = 2048;     // 8 blocks/CU -> 8 waves/SIMD; 2 strides each

    hipLaunchKernelGGL(funcblock_kernel, dim3(grid), dim3(block), 0, stream,
                       x, W_prod, b_prod, W_sum, b_sum,
                       w_dln, W_ln, w_dsin, W_sin, w_dcos, W_cos,
                       w_de, W_e, w_dtanh, W_tanh, out, B);
}

// Round 4
// 105.050 us; speedup vs baseline: 1.5379x; 1.0140x over previous
//
#include <hip/hip_runtime.h>

// Phase 1: half-wave (32 lanes) per row, float4/lane loads. Product-block dot
// is computed in log2 space with hardware v_log_f32 (__log2f); sum-block dot
// in plain f32. Butterfly-reduce both, park raw (p2, s) per row in LDS.
// Phase 2: all 64 lanes run the exp2 + 5-stage transcendental chain
// wave-parallel (amortized 32x) and store coalesced outputs.

__global__ __launch_bounds__(256) void funcblock_kernel(
    const float* __restrict__ x,
    const float* __restrict__ W_prod, const float* __restrict__ b_prod,
    const float* __restrict__ W_sum,  const float* __restrict__ b_sum,
    const float* __restrict__ w_dln,  const float* __restrict__ W_ln,
    const float* __restrict__ w_dsin, const float* __restrict__ W_sin,
    const float* __restrict__ w_dcos, const float* __restrict__ W_cos,
    const float* __restrict__ w_de,   const float* __restrict__ W_e,
    const float* __restrict__ w_dtanh,const float* __restrict__ W_tanh,
    float* __restrict__ out, int B)
{
    __shared__ float pbuf[4][64];   // per-wave strip: product-dot (log2 space)
    __shared__ float sbuf[4][64];   // per-wave strip: sum-dot

    const int tid   = threadIdx.x;
    const int hlane = tid & 31;        // lane within half-wave
    const int half  = (tid >> 5) & 1;  // which half of the wave64
    const int wid   = tid >> 6;        // wave index in block (0..3)
    const int lane  = tid & 63;

    // Loop-invariant weights -> registers
    const float4 wp = reinterpret_cast<const float4*>(W_prod)[hlane];
    const float4 ws = reinterpret_cast<const float4*>(W_sum)[hlane];
    const float ws128 = W_sum[128];
    // exp(p_ln + bp) == exp2(p_log2 + bp*log2(e))
    const float bp2 = b_prod[0] * 1.44269504088896340736f;
    const float bs = b_sum[0];
    const float wdln  = w_dln[0],  wln0  = W_ln[0],  wln1  = W_ln[1];
    const float wdsin = w_dsin[0], wsin0 = W_sin[0], wsin1 = W_sin[1];
    const float wdcos = w_dcos[0], wcos0 = W_cos[0], wcos1 = W_cos[1];
    const float wde   = w_de[0],   we0   = W_e[0],   we1   = W_e[1];
    const float wdtanh= w_dtanh[0],wt0   = W_tanh[0],wt1   = W_tanh[1];

    const int rows_per_block = 256;    // 4 waves x 64 rows
    for (int base = blockIdx.x * rows_per_block; base < B;
         base += gridDim.x * rows_per_block) {
        const int wbase = base + wid * 64;

        // ---- Phase 1: dot products for 64 rows (2 rows per iteration) ----
        #pragma unroll 2
        for (int it = 0; it < 32; ++it) {
            const int row = wbase + half * 32 + it;
            float p = 0.0f, s = 0.0f;
            if (row < B) {
                const float4 xv =
                    reinterpret_cast<const float4*>(x + (size_t)row * 128)[hlane];
                // hardware log2 (v_log_f32, <=1 ulp); ln-space fold done via bp2/exp2
                p  = __log2f(__builtin_fabsf(xv.x)) * wp.x;
                p += __log2f(__builtin_fabsf(xv.y)) * wp.y;
                p += __log2f(__builtin_fabsf(xv.z)) * wp.z;
                p += __log2f(__builtin_fabsf(xv.w)) * wp.w;
                s  = xv.x * ws.x + xv.y * ws.y + xv.z * ws.z + xv.w * ws.w;
            }
            #pragma unroll
            for (int m = 16; m >= 1; m >>= 1) {   // stays within the 32-lane half
                p += __shfl_xor(p, m, 64);
                s += __shfl_xor(s, m, 64);
            }
            if (hlane == 0) {
                pbuf[wid][half * 32 + it] = p;
                sbuf[wid][half * 32 + it] = s;
            }
        }
        __syncthreads();

        // ---- Phase 2: chain for 64 rows, one per lane, all lanes active ----
        const int row = wbase + lane;
        const float p = pbuf[wid][lane];
        const float s = sbuf[wid][lane];
        __syncthreads();   // LDS strips free for next block-iteration

        const float x_prod = __builtin_amdgcn_exp2f(p + bp2);  // v_exp_f32
        float h = s + x_prod * ws128 + bs;
        float d;
        d = fmaxf(logf(fabsf(h)) * wdln, 0.0f);  h = d * wln0  + h * wln1;
        d = fmaxf(sinf(h) * wdsin, 0.0f);        h = d * wsin0 + h * wsin1;
        d = fmaxf(cosf(h) * wdcos, 0.0f);        h = d * wcos0 + h * wcos1;
        d = fmaxf(expf(h) * wde,   0.0f);        h = d * we0   + h * we1;
        d = fmaxf(tanhf(h) * wdtanh, 0.0f);      h = d * wt0   + h * wt1;
        if (row < B) out[row] = h;
    }
}

extern "C" void kernel_launch(void* const* d_in, const int* in_sizes, int n_in,
                              void* d_out, int out_size, void* d_ws, size_t ws_size,
                              hipStream_t stream) {
    const float* x      = (const float*)d_in[0];
    const float* W_prod = (const float*)d_in[1];
    const float* b_prod = (const float*)d_in[2];
    const float* W_sum  = (const float*)d_in[3];
    const float* b_sum  = (const float*)d_in[4];
    const float* w_dln  = (const float*)d_in[5];
    const float* W_ln   = (const float*)d_in[6];
    const float* w_dsin = (const float*)d_in[7];
    const float* W_sin  = (const float*)d_in[8];
    const float* w_dcos = (const float*)d_in[9];
    const float* W_cos  = (const float*)d_in[10];
    const float* w_de   = (const float*)d_in[11];
    const float* W_e    = (const float*)d_in[12];
    const float* w_dtanh= (const float*)d_in[13];
    const float* W_tanh = (const float*)d_in[14];
    float* out = (float*)d_out;

    const int B = out_size;     // 1048576 rows
    const int block = 256;      // 4 waves
    const int grid  = 2048;     // 8 blocks/CU; 2 grid-strides

    hipLaunchKernelGGL(funcblock_kernel, dim3(grid), dim3(block), 0, stream,
                       x, W_prod, b_prod, W_sum, b_sum,
                       w_dln, W_ln, w_dsin, W_sin, w_dcos, W_cos,
                       w_de, W_e, w_dtanh, W_tanh, out, B);
}

// Round 5
// 100.846 us; speedup vs baseline: 1.6020x; 1.0417x over previous
//
#include <hip/hip_runtime.h>

// 8 lanes per row, 8 rows per wave-iteration. Each lane loads 4 independent
// float4s (row-chunk u*16B + j*128B: per instruction the wave reads 8 rows x
// 128B contiguous segments). Product dot in log2 space (v_log_f32), sum dot
// in f32; 3-step butterfly reduce within 8-lane groups (vs 5-step/32-lane
// before: 13x fewer DS ops, 3x shorter serial chain). Lane u==0 parks (p,s)
// in LDS; after 64 rows all 64 lanes run the transcendental chain
// wave-parallel and store coalesced.

__global__ __launch_bounds__(256) void funcblock_kernel(
    const float* __restrict__ x,
    const float* __restrict__ W_prod, const float* __restrict__ b_prod,
    const float* __restrict__ W_sum,  const float* __restrict__ b_sum,
    const float* __restrict__ w_dln,  const float* __restrict__ W_ln,
    const float* __restrict__ w_dsin, const float* __restrict__ W_sin,
    const float* __restrict__ w_dcos, const float* __restrict__ W_cos,
    const float* __restrict__ w_de,   const float* __restrict__ W_e,
    const float* __restrict__ w_dtanh,const float* __restrict__ W_tanh,
    float* __restrict__ out, int B)
{
    __shared__ float pbuf[4][64];   // per-wave strip: product-dot (log2 space)
    __shared__ float sbuf[4][64];   // per-wave strip: sum-dot

    const int tid  = threadIdx.x;
    const int lane = tid & 63;
    const int wid  = tid >> 6;      // wave in block (0..3)
    const int u    = lane & 7;      // sub-lane within 8-lane row group
    const int g    = lane >> 3;     // row group (0..7)

    // Per-lane weight fragments: float4 indices u + 8j (matches x load pattern)
    float4 wp[4], ws[4];
    #pragma unroll
    for (int j = 0; j < 4; ++j) {
        wp[j] = reinterpret_cast<const float4*>(W_prod)[u + 8 * j];
        ws[j] = reinterpret_cast<const float4*>(W_sum)[u + 8 * j];
    }
    const float ws128 = W_sum[128];
    const float bp2 = b_prod[0] * 1.44269504088896340736f;  // exp -> exp2 fold
    const float bs = b_sum[0];
    const float wdln  = w_dln[0],  wln0  = W_ln[0],  wln1  = W_ln[1];
    const float wdsin = w_dsin[0], wsin0 = W_sin[0], wsin1 = W_sin[1];
    const float wdcos = w_dcos[0], wcos0 = W_cos[0], wcos1 = W_cos[1];
    const float wde   = w_de[0],   we0   = W_e[0],   we1   = W_e[1];
    const float wdtanh= w_dtanh[0],wt0   = W_tanh[0],wt1   = W_tanh[1];

    const int rows_per_block = 256;    // 4 waves x 64 rows
    for (int base = blockIdx.x * rows_per_block; base < B;
         base += gridDim.x * rows_per_block) {
        const int wbase = base + wid * 64;

        // ---- Phase 1: dot products, 8 rows per iteration ----
        #pragma unroll 2
        for (int it = 0; it < 8; ++it) {
            const int row = wbase + it * 8 + g;
            float p = 0.0f, s = 0.0f;
            if (row < B) {
                const float4* xr =
                    reinterpret_cast<const float4*>(x + (size_t)row * 128);
                float4 xv[4];
                #pragma unroll
                for (int j = 0; j < 4; ++j) xv[j] = xr[u + 8 * j];  // 4 indep loads
                #pragma unroll
                for (int j = 0; j < 4; ++j) {
                    p += __log2f(__builtin_fabsf(xv[j].x)) * wp[j].x;
                    p += __log2f(__builtin_fabsf(xv[j].y)) * wp[j].y;
                    p += __log2f(__builtin_fabsf(xv[j].z)) * wp[j].z;
                    p += __log2f(__builtin_fabsf(xv[j].w)) * wp[j].w;
                    s += xv[j].x * ws[j].x + xv[j].y * ws[j].y
                       + xv[j].z * ws[j].z + xv[j].w * ws[j].w;
                }
            }
            #pragma unroll
            for (int m = 4; m >= 1; m >>= 1) {   // 3 steps, within 8-lane group
                p += __shfl_xor(p, m, 64);
                s += __shfl_xor(s, m, 64);
            }
            if (u == 0) {
                pbuf[wid][it * 8 + g] = p;
                sbuf[wid][it * 8 + g] = s;
            }
        }
        __syncthreads();

        // ---- Phase 2: chain for 64 rows, one per lane, all lanes active ----
        const int row = wbase + lane;
        const float p = pbuf[wid][lane];
        const float s = sbuf[wid][lane];
        __syncthreads();   // strips free for next block-iteration

        const float x_prod = __builtin_amdgcn_exp2f(p + bp2);  // v_exp_f32
        float h = s + x_prod * ws128 + bs;
        float d;
        d = fmaxf(logf(fabsf(h)) * wdln, 0.0f);  h = d * wln0  + h * wln1;
        d = fmaxf(sinf(h) * wdsin, 0.0f);        h = d * wsin0 + h * wsin1;
        d = fmaxf(cosf(h) * wdcos, 0.0f);        h = d * wcos0 + h * wcos1;
        d = fmaxf(expf(h) * wde,   0.0f);        h = d * we0   + h * we1;
        d = fmaxf(tanhf(h) * wdtanh, 0.0f);      h = d * wt0   + h * wt1;
        if (row < B) out[row] = h;
    }
}

extern "C" void kernel_launch(void* const* d_in, const int* in_sizes, int n_in,
                              void* d_out, int out_size, void* d_ws, size_t ws_size,
                              hipStream_t stream) {
    const float* x      = (const float*)d_in[0];
    const float* W_prod = (const float*)d_in[1];
    const float* b_prod = (const float*)d_in[2];
    const float* W_sum  = (const float*)d_in[3];
    const float* b_sum  = (const float*)d_in[4];
    const float* w_dln  = (const float*)d_in[5];
    const float* W_ln   = (const float*)d_in[6];
    const float* w_dsin = (const float*)d_in[7];
    const float* W_sin  = (const float*)d_in[8];
    const float* w_dcos = (const float*)d_in[9];
    const float* W_cos  = (const float*)d_in[10];
    const float* w_de   = (const float*)d_in[11];
    const float* W_e    = (const float*)d_in[12];
    const float* w_dtanh= (const float*)d_in[13];
    const float* W_tanh = (const float*)d_in[14];
    float* out = (float*)d_out;

    const int B = out_size;     // 1048576 rows
    const int block = 256;      // 4 waves
    const int grid  = 2048;     // rows_per_block=256 -> 2 grid-strides

    hipLaunchKernelGGL(funcblock_kernel, dim3(grid), dim3(block), 0, stream,
                       x, W_prod, b_prod, W_sum, b_sum,
                       w_dln, W_ln, w_dsin, W_sin, w_dcos, W_cos,
                       w_de, W_e, w_dtanh, W_tanh, out, B);
}